// Round 2
// baseline (5615.002 us; speedup 1.0000x reference)
//
#include <hip/hip_runtime.h>
#include <cstdint>
#include <cstddef>

#define GDIM 512

// ---------------------------------------------------------------- hash table
__device__ __forceinline__ int hash_lookup(int key, const int* __restrict__ keys,
                                           const int* __restrict__ vals, unsigned capmask) {
  unsigned slot = ((unsigned)key * 2654435761u) & capmask;
  while (true) {
    int kk = keys[slot];
    if (kk == key) return vals[slot];
    if (kk == -1) return -1;
    slot = (slot + 1) & capmask;
  }
}

__global__ void k_build_table(const int* __restrict__ coords, int n, int sh, int Gs,
                              int* __restrict__ keys, int* __restrict__ vals, unsigned capmask) {
  int i = blockIdx.x * blockDim.x + threadIdx.x;
  if (i >= n) return;
  int b = coords[4 * i];
  int key = ((b * Gs + (coords[4 * i + 1] >> sh)) * Gs + (coords[4 * i + 2] >> sh)) * Gs +
            (coords[4 * i + 3] >> sh);
  unsigned slot = ((unsigned)key * 2654435761u) & capmask;
  while (true) {
    int prev = atomicCAS(&keys[slot], -1, key);
    if (prev == -1) { vals[slot] = i; return; }
    slot = (slot + 1) & capmask;
  }
}

// ------------------------------------------------- conv: pair list per offset
__global__ void k_query_pairs(const int* __restrict__ oc, int m, int sh, int Gs,
                              const int* __restrict__ keys, const int* __restrict__ vals,
                              unsigned capmask, int* __restrict__ pout, int* __restrict__ pin,
                              int* __restrict__ counts, int mcap) {
  int t = blockIdx.x * blockDim.x + threadIdx.x;
  if (t >= m * 27) return;
  int o = t / 27, k = t - o * 27;
  int stride = 1 << sh;
  int dx = k / 9 - 1, dy = (k / 3) % 3 - 1, dz = k % 3 - 1;
  int b  = oc[4 * o];
  int qx = oc[4 * o + 1] + dx * stride;
  int qy = oc[4 * o + 2] + dy * stride;
  int qz = oc[4 * o + 3] + dz * stride;
  if ((unsigned)qx >= GDIM || (unsigned)qy >= GDIM || (unsigned)qz >= GDIM) return;
  int key = ((b * Gs + (qx >> sh)) * Gs + (qy >> sh)) * Gs + (qz >> sh);
  int i = hash_lookup(key, keys, vals, capmask);
  if (i >= 0) {
    int p = atomicAdd(&counts[k], 1);
    pout[k * mcap + p] = o;
    pin [k * mcap + p] = i;
  }
}

// ----------------------------------------------- gather-GEMM-scatter (fp32)
// tile: 64 pairs x 64 cout, K-tile 16, 256 threads, 4x4 acc/thread
__global__ __launch_bounds__(256) void k_conv_gemm(
    const float* __restrict__ F, const float* __restrict__ W, float* __restrict__ out,
    const int* __restrict__ pout, const int* __restrict__ pin, const int* __restrict__ counts,
    int cin, int cout, int mcap) {
  int k = blockIdx.z;
  int cnt = counts[k];
  int p0 = blockIdx.x * 64;
  if (p0 >= cnt) return;
  int np = min(64, cnt - p0);
  int c0 = blockIdx.y * 64;

  __shared__ float As[64][17];
  __shared__ float Bs[16][64];
  __shared__ int rows_in[64];

  int tid = threadIdx.x;
  if (tid < 64) rows_in[tid] = (tid < np) ? pin[k * mcap + p0 + tid] : -1;
  __syncthreads();

  int tx = tid & 15, ty = tid >> 4;
  float acc[4][4] = {{0.f}};
  const float* Wk = W + (size_t)k * cin * cout;

  for (int kk = 0; kk < cin; kk += 16) {
    #pragma unroll
    for (int e = tid; e < 64 * 16; e += 256) {
      int pr = e >> 4, kc = e & 15;
      int irow = rows_in[pr];
      As[pr][kc] = (irow >= 0) ? F[(size_t)irow * cin + kk + kc] : 0.f;
    }
    #pragma unroll
    for (int e = tid; e < 16 * 64; e += 256) {
      int kr = e >> 6, cc = e & 63;
      int c = c0 + cc;
      Bs[kr][cc] = (c < cout) ? Wk[(size_t)(kk + kr) * cout + c] : 0.f;
    }
    __syncthreads();
    #pragma unroll
    for (int q = 0; q < 16; ++q) {
      float a0 = As[ty * 4 + 0][q], a1 = As[ty * 4 + 1][q];
      float a2 = As[ty * 4 + 2][q], a3 = As[ty * 4 + 3][q];
      float b0 = Bs[q][tx * 4 + 0], b1 = Bs[q][tx * 4 + 1];
      float b2 = Bs[q][tx * 4 + 2], b3 = Bs[q][tx * 4 + 3];
      acc[0][0] += a0 * b0; acc[0][1] += a0 * b1; acc[0][2] += a0 * b2; acc[0][3] += a0 * b3;
      acc[1][0] += a1 * b0; acc[1][1] += a1 * b1; acc[1][2] += a1 * b2; acc[1][3] += a1 * b3;
      acc[2][0] += a2 * b0; acc[2][1] += a2 * b1; acc[2][2] += a2 * b2; acc[2][3] += a2 * b3;
      acc[3][0] += a3 * b0; acc[3][1] += a3 * b1; acc[3][2] += a3 * b2; acc[3][3] += a3 * b3;
    }
    __syncthreads();
  }

  #pragma unroll
  for (int i = 0; i < 4; ++i) {
    int pr = ty * 4 + i;
    if (pr < np) {
      int orow = pout[k * mcap + p0 + pr];
      #pragma unroll
      for (int j = 0; j < 4; ++j) {
        int c = c0 + tx * 4 + j;
        if (c < cout) atomicAdd(&out[(size_t)orow * cout + c], acc[i][j]);
      }
    }
  }
}

// ------------------------------------------------------------------ maxpool
__global__ void k_query_idx(const int* __restrict__ oc, int m, int sh, int Gs,
                            const int* __restrict__ keys, const int* __restrict__ vals,
                            unsigned capmask, int* __restrict__ idx) {
  int t = blockIdx.x * blockDim.x + threadIdx.x;
  if (t >= m * 27) return;
  int o = t / 27, k = t - o * 27;
  int stride = 1 << sh;
  int dx = k / 9 - 1, dy = (k / 3) % 3 - 1, dz = k % 3 - 1;
  int b  = oc[4 * o];
  int qx = oc[4 * o + 1] + dx * stride;
  int qy = oc[4 * o + 2] + dy * stride;
  int qz = oc[4 * o + 3] + dz * stride;
  int res = -1;
  if ((unsigned)qx < GDIM && (unsigned)qy < GDIM && (unsigned)qz < GDIM) {
    int key = ((b * Gs + (qx >> sh)) * Gs + (qy >> sh)) * Gs + (qz >> sh);
    res = hash_lookup(key, keys, vals, capmask);
  }
  idx[t] = res;
}

__global__ void k_maxpool(const float* __restrict__ F, float* __restrict__ out,
                          const int* __restrict__ idx, int m, int C) {
  long long t = (long long)blockIdx.x * blockDim.x + threadIdx.x;
  if (t >= (long long)m * C) return;
  int o = (int)(t / C), c = (int)(t - (long long)o * C);
  float best = -3e38f;
  #pragma unroll 1
  for (int k = 0; k < 27; ++k) {
    int i = idx[o * 27 + k];
    if (i >= 0) best = fmaxf(best, F[(size_t)i * C + c]);
  }
  out[t] = best;
}

// -------------------------------------------------------- slice / gather / mlp
__global__ void k_slice_idx(const int* __restrict__ coords, int n, int sh, int Gs,
                            const int* __restrict__ keys, const int* __restrict__ vals,
                            unsigned capmask, int* __restrict__ sidx) {
  int i = blockIdx.x * blockDim.x + threadIdx.x;
  if (i >= n) return;
  int b = coords[4 * i];
  int key = ((b * Gs + (coords[4 * i + 1] >> sh)) * Gs + (coords[4 * i + 2] >> sh)) * Gs +
            (coords[4 * i + 3] >> sh);
  int v = hash_lookup(key, keys, vals, capmask);
  sidx[i] = (v < 0) ? 0 : v;
}

__global__ void k_gather_cols(const float* __restrict__ src, int C, const int* __restrict__ sidx,
                              float* __restrict__ dst, int dstC, int colOff, int n) {
  long long t = (long long)blockIdx.x * blockDim.x + threadIdx.x;
  if (t >= (long long)n * C) return;
  int o = (int)(t / C), c = (int)(t - (long long)o * C);
  dst[(size_t)o * dstC + colOff + c] = src[(size_t)sidx[o] * C + c];
}

__global__ void k_mlp(const float* __restrict__ feats, const float* __restrict__ w,
                      float* __restrict__ x, int n) {
  int t = blockIdx.x * blockDim.x + threadIdx.x;
  if (t >= n * 32) return;
  x[t] = feats[t >> 5] * w[t & 31];
}

// ----------------------------------------------------------------------- BN
__global__ void k_bn_stats(const float* __restrict__ x, int m, int C, float* __restrict__ sums) {
  int r0 = blockIdx.x * 256;
  int rend = min(r0 + 256, m);
  for (int c = threadIdx.x; c < C; c += 256) {
    float s = 0.f, s2 = 0.f;
    for (int r = r0; r < rend; ++r) {
      float v = x[(size_t)r * C + c];
      s += v; s2 += v * v;
    }
    atomicAdd(&sums[c], s);
    atomicAdd(&sums[C + c], s2);
  }
}

__global__ void k_bn_finalize(const float* __restrict__ sums, const float* __restrict__ gamma,
                              const float* __restrict__ beta, int C, float inv_m,
                              float* __restrict__ ab) {
  for (int c = threadIdx.x; c < C; c += 256) {
    float mu  = sums[c] * inv_m;
    float var = sums[C + c] * inv_m - mu * mu;
    float a = rsqrtf(var + 1e-5f) * gamma[c];
    ab[c] = a;
    ab[C + c] = beta[c] - mu * a;
  }
}

__global__ void k_bn_apply(float* __restrict__ x, long long total, int C,
                           const float* __restrict__ ab) {
  long long t = (long long)blockIdx.x * blockDim.x + threadIdx.x;
  if (t >= total) return;
  int c = (int)(t % C);
  float y = ab[c] * x[t] + ab[C + c];
  x[t] = fmaxf(y, 0.01f * y);  // leaky relu, slope 0.01
}

// ---------------------------------------------------------------------- host
extern "C" void kernel_launch(void* const* d_in, const int* in_sizes, int n_in,
                              void* d_out, int out_size, void* d_ws, size_t ws_size,
                              hipStream_t stream) {
  (void)n_in; (void)out_size; (void)ws_size;
  // setup_inputs() dict order (levels appended LAST via inp.update(levels)):
  //  0 feats, 1 coords, 2 w_mlp, 3 gm, 4 bm, 5 W1, 6 g1, 7 b1, 8 W2, 9 g2, 10 b2,
  // 11 W3, 12 g3, 13 b3, 14 W4, 15 g4, 16 b4, 17 W5a, 18 g5a, 19 b5a,
  // 20 W5b, 21 g5b, 22 b5b, 23 W5c, 24 g5c, 25 b5c, 26 c2, 27 c4, 28 c8,
  // 29 c16, 30 c32, 31 c64, 32 c128
  const float* feats  = (const float*)d_in[0];
  const int*   coords = (const int*)d_in[1];
  const float* w_mlp = (const float*)d_in[2];
  const float* gm  = (const float*)d_in[3];  const float* bm  = (const float*)d_in[4];
  const float* W1  = (const float*)d_in[5];  const float* g1  = (const float*)d_in[6];  const float* b1  = (const float*)d_in[7];
  const float* W2  = (const float*)d_in[8];  const float* g2  = (const float*)d_in[9];  const float* b2  = (const float*)d_in[10];
  const float* W3  = (const float*)d_in[11]; const float* g3  = (const float*)d_in[12]; const float* b3  = (const float*)d_in[13];
  const float* W4  = (const float*)d_in[14]; const float* g4  = (const float*)d_in[15]; const float* b4  = (const float*)d_in[16];
  const float* W5a = (const float*)d_in[17]; const float* g5a = (const float*)d_in[18]; const float* b5a = (const float*)d_in[19];
  const float* W5b = (const float*)d_in[20]; const float* g5b = (const float*)d_in[21]; const float* b5b = (const float*)d_in[22];
  const float* W5c = (const float*)d_in[23]; const float* g5c = (const float*)d_in[24]; const float* b5c = (const float*)d_in[25];
  const int*   lvl[7];
  for (int i = 0; i < 7; ++i) lvl[i] = (const int*)d_in[26 + i];

  const int N = in_sizes[0];   // feats is (N,1)
  int nl[7];
  for (int i = 0; i < 7; ++i) nl[i] = in_sizes[26 + i] / 4;
  const int n2 = nl[0], n4 = nl[1], n8 = nl[2], n16 = nl[3], n32 = nl[4], n64 = nl[5], n128 = nl[6];

  char* ws = (char*)d_ws;
  size_t off = 0;
  auto alloc = [&](size_t bytes) -> char* {
    off = (off + 255) & ~(size_t)255;
    char* p = ws + off;
    off += bytes;
    return p;
  };

  // hash tables: coords@1, c2@2, c4@4, c8@8, c16@16, c32@32, c64@64, c128@128
  struct Tab { int* keys; int* vals; unsigned mask; int sh; int Gs; int n; const int* src; };
  Tab tab[8];
  const int* tsrc[8] = {coords, lvl[0], lvl[1], lvl[2], lvl[3], lvl[4], lvl[5], lvl[6]};
  int tn[8] = {N, n2, n4, n8, n16, n32, n64, n128};
  for (int i = 0; i < 8; ++i) {
    int cap = 64;
    while (cap < 2 * tn[i]) cap <<= 1;
    tab[i].keys = (int*)alloc((size_t)cap * 4);
    tab[i].vals = (int*)alloc((size_t)cap * 4);
    tab[i].mask = (unsigned)(cap - 1);
    tab[i].sh = i;                 // stride = 1<<i
    tab[i].Gs = GDIM >> i;
    tab[i].n = tn[i];
    tab[i].src = tsrc[i];
  }

  int* pout   = (int*)alloc((size_t)27 * N * 4);
  int* pin    = (int*)alloc((size_t)27 * N * 4);
  int* counts = (int*)alloc(256);
  int* idxbuf = (int*)alloc((size_t)27 * N * 4);
  int* sidx[4];
  for (int i = 0; i < 4; ++i) sidx[i] = (int*)alloc((size_t)N * 4);
  float* bnsum = (float*)alloc(2 * 1024 * 4);
  float* bnab  = (float*)alloc(2 * 1024 * 4);

  auto mx = [](size_t a, size_t b) { return a > b ? a : b; };
  size_t szA = mx(mx((size_t)N * 32, (size_t)n4 * 64), (size_t)n64 * 128) * 4;   // x / t2 / t4
  size_t szB = mx(mx((size_t)N * 48, (size_t)n16 * 96), (size_t)n2 * 256) * 4;   // t1 / t3 / t5a
  float* RA = (float*)alloc(szA);
  float* RB = (float*)alloc(szB);
  float* y1 = (float*)alloc((size_t)n2 * 48 * 4);
  float* y2 = (float*)alloc((size_t)n8 * 64 * 4);
  float* y3 = (float*)alloc((size_t)n32 * 96 * 4);
  float* y4 = (float*)alloc((size_t)n128 * 128 * 4);
  size_t szG = mx((size_t)N * 336, (size_t)n4 * 512) * 4;                         // xc / t5b
  float* RG = (float*)alloc(szG);

  // build all hash tables
  for (int i = 0; i < 8; ++i)
    hipMemsetAsync(tab[i].keys, 0xFF, (size_t)(tab[i].mask + 1) * 4, stream);
  for (int i = 0; i < 8; ++i)
    k_build_table<<<(tab[i].n + 255) / 256, 256, 0, stream>>>(
        tab[i].src, tab[i].n, tab[i].sh, tab[i].Gs, tab[i].keys, tab[i].vals, tab[i].mask);

  auto conv = [&](const float* F, const int* oc, int m, const Tab& t,
                  const float* W, int cin, int cout, float* out) {
    hipMemsetAsync(counts, 0, 27 * 4, stream);
    int thr = m * 27;
    k_query_pairs<<<(thr + 255) / 256, 256, 0, stream>>>(
        oc, m, t.sh, t.Gs, t.keys, t.vals, t.mask, pout, pin, counts, N);
    hipMemsetAsync(out, 0, (size_t)m * cout * 4, stream);
    dim3 grid((m + 63) / 64, (cout + 63) / 64, 27);
    k_conv_gemm<<<grid, 256, 0, stream>>>(F, W, out, pout, pin, counts, cin, cout, N);
  };
  auto bn = [&](float* x, int m, int C, const float* gamma, const float* beta) {
    hipMemsetAsync(bnsum, 0, (size_t)2 * C * 4, stream);
    k_bn_stats<<<(m + 255) / 256, 256, 0, stream>>>(x, m, C, bnsum);
    k_bn_finalize<<<1, 256, 0, stream>>>(bnsum, gamma, beta, C, 1.0f / (float)m, bnab);
    long long total = (long long)m * C;
    k_bn_apply<<<(int)((total + 255) / 256), 256, 0, stream>>>(x, total, C, bnab);
  };
  auto pool = [&](const float* F, const int* oc, int m, const Tab& t, int C, float* out) {
    int thr = m * 27;
    k_query_idx<<<(thr + 255) / 256, 256, 0, stream>>>(
        oc, m, t.sh, t.Gs, t.keys, t.vals, t.mask, idxbuf);
    long long total = (long long)m * C;
    k_maxpool<<<(int)((total + 255) / 256), 256, 0, stream>>>(F, out, idxbuf, m, C);
  };

  // ---- network ----
  float* x = RA;
  k_mlp<<<(N * 32 + 255) / 256, 256, 0, stream>>>(feats, w_mlp, x, N);
  bn(x, N, 32, gm, bm);

  float* t1 = RB;
  conv(x, coords, N, tab[0], W1, 32, 48, t1);
  bn(t1, N, 48, g1, b1);
  pool(t1, lvl[0], n2, tab[0], 48, y1);

  float* t2 = RA;
  conv(y1, lvl[1], n4, tab[1], W2, 48, 64, t2);
  bn(t2, n4, 64, g2, b2);
  pool(t2, lvl[2], n8, tab[2], 64, y2);

  float* t3 = RB;
  conv(y2, lvl[3], n16, tab[3], W3, 64, 96, t3);
  bn(t3, n16, 96, g3, b3);
  pool(t3, lvl[4], n32, tab[4], 96, y3);

  float* t4 = RA;
  conv(y3, lvl[5], n64, tab[5], W4, 96, 128, t4);
  bn(t4, n64, 128, g4, b4);
  pool(t4, lvl[6], n128, tab[6], 128, y4);

  // slice_to_field -> xc
  k_slice_idx<<<(N + 255) / 256, 256, 0, stream>>>(coords, N, tab[1].sh, tab[1].Gs,
                                                   tab[1].keys, tab[1].vals, tab[1].mask, sidx[0]);
  k_slice_idx<<<(N + 255) / 256, 256, 0, stream>>>(coords, N, tab[3].sh, tab[3].Gs,
                                                   tab[3].keys, tab[3].vals, tab[3].mask, sidx[1]);
  k_slice_idx<<<(N + 255) / 256, 256, 0, stream>>>(coords, N, tab[5].sh, tab[5].Gs,
                                                   tab[5].keys, tab[5].vals, tab[5].mask, sidx[2]);
  k_slice_idx<<<(N + 255) / 256, 256, 0, stream>>>(coords, N, tab[7].sh, tab[7].Gs,
                                                   tab[7].keys, tab[7].vals, tab[7].mask, sidx[3]);
  float* xc = RG;
  k_gather_cols<<<(int)(((long long)N * 48 + 255) / 256), 256, 0, stream>>>(y1, 48, sidx[0], xc, 336, 0, N);
  k_gather_cols<<<(int)(((long long)N * 64 + 255) / 256), 256, 0, stream>>>(y2, 64, sidx[1], xc, 336, 48, N);
  k_gather_cols<<<(int)(((long long)N * 96 + 255) / 256), 256, 0, stream>>>(y3, 96, sidx[2], xc, 336, 112, N);
  k_gather_cols<<<(int)(((long long)N * 128 + 255) / 256), 256, 0, stream>>>(y4, 128, sidx[3], xc, 336, 208, N);

  float* t5a = RB;
  conv(xc, lvl[0], n2, tab[0], W5a, 336, 256, t5a);
  bn(t5a, n2, 256, g5a, b5a);

  float* t5b = RG;  // xc dead after conv5a
  conv(t5a, lvl[1], n4, tab[1], W5b, 256, 512, t5b);
  bn(t5b, n4, 512, g5b, b5b);

  float* outp = (float*)d_out;
  conv(t5b, lvl[2], n8, tab[2], W5c, 512, 1024, outp);
  bn(outp, n8, 1024, g5c, b5c);
}

// Round 3
// 3638.120 us; speedup vs baseline: 1.5434x; 1.5434x over previous
//
#include <hip/hip_runtime.h>
#include <cstdint>
#include <cstddef>

#define GDIM 512

typedef __attribute__((ext_vector_type(8))) short short8;
typedef __attribute__((ext_vector_type(4))) float f32x4;

__device__ __forceinline__ short f2bf(float f) {
  unsigned u = __float_as_uint(f);
  u = u + 0x7fffu + ((u >> 16) & 1u);  // round-to-nearest-even
  return (short)(u >> 16);
}

// ---------------------------------------------------------------- hash table
__device__ __forceinline__ int hash_lookup(int key, const int* __restrict__ keys,
                                           const int* __restrict__ vals, unsigned capmask) {
  unsigned slot = ((unsigned)key * 2654435761u) & capmask;
  while (true) {
    int kk = keys[slot];
    if (kk == key) return vals[slot];
    if (kk == -1) return -1;
    slot = (slot + 1) & capmask;
  }
}

__global__ void k_build_table(const int* __restrict__ coords, int n, int sh, int Gs,
                              int* __restrict__ keys, int* __restrict__ vals, unsigned capmask) {
  int i = blockIdx.x * blockDim.x + threadIdx.x;
  if (i >= n) return;
  int b = coords[4 * i];
  int key = ((b * Gs + (coords[4 * i + 1] >> sh)) * Gs + (coords[4 * i + 2] >> sh)) * Gs +
            (coords[4 * i + 3] >> sh);
  unsigned slot = ((unsigned)key * 2654435761u) & capmask;
  while (true) {
    int prev = atomicCAS(&keys[slot], -1, key);
    if (prev == -1) { vals[slot] = i; return; }
    slot = (slot + 1) & capmask;
  }
}

// ------------------------------------------------- conv: pair list per offset
__global__ void k_query_pairs(const int* __restrict__ oc, int m, int sh, int Gs,
                              const int* __restrict__ keys, const int* __restrict__ vals,
                              unsigned capmask, int* __restrict__ pout, int* __restrict__ pin,
                              int* __restrict__ counts, int mcap) {
  int t = blockIdx.x * blockDim.x + threadIdx.x;
  if (t >= m * 27) return;
  int o = t / 27, k = t - o * 27;
  int stride = 1 << sh;
  int dx = k / 9 - 1, dy = (k / 3) % 3 - 1, dz = k % 3 - 1;
  int b  = oc[4 * o];
  int qx = oc[4 * o + 1] + dx * stride;
  int qy = oc[4 * o + 2] + dy * stride;
  int qz = oc[4 * o + 3] + dz * stride;
  if ((unsigned)qx >= GDIM || (unsigned)qy >= GDIM || (unsigned)qz >= GDIM) return;
  int key = ((b * Gs + (qx >> sh)) * Gs + (qy >> sh)) * Gs + (qz >> sh);
  int i = hash_lookup(key, keys, vals, capmask);
  if (i >= 0) {
    int p = atomicAdd(&counts[k], 1);
    pout[k * mcap + p] = o;
    pin [k * mcap + p] = i;
  }
}

// --------------------------------------------- MFMA bf16 gather-GEMM-scatter
// Block: 64 pairs x 128 cout columns (looped over full cout), A-tile resident
// in LDS per 256-wide K-slab. 4 waves, each 32x64 subtile via 2x4 MFMA 16x16x32.
// AFP32: A is fp32 + fused bn(ab)+leakyrelu -> bf16 during staging.
template<bool AFP32>
__global__ __launch_bounds__(256) void k_conv_mfma(
    const void* __restrict__ Fv, const float* __restrict__ ab,
    const short* __restrict__ Wt,  // bf16 [27][cout][cin]
    float* __restrict__ out,
    const int* __restrict__ pout, const int* __restrict__ pin,
    const int* __restrict__ counts, int cin, int cin_pad, int cout, int mcap) {
  int k = blockIdx.z;
  int cnt = counts[k];
  int p0 = blockIdx.x * 64;
  if (p0 >= cnt) return;
  int np = min(64, cnt - p0);

  extern __shared__ char smem[];
  const int aStride = (cin_pad < 256 ? cin_pad : 256) + 8;  // +8 bf16 pad: 2-way max
  short* Alds = (short*)smem;                  // 64 x aStride
  short* Blds = Alds + 64 * aStride;           // 128 x 40 (32 k + 8 pad)
  int* rows_out = (int*)(Blds + 128 * 40);
  int* rows_in  = rows_out + 64;

  int tid = threadIdx.x;
  if (tid < 64) {
    rows_out[tid] = (tid < np) ? pout[k * mcap + p0 + tid] : -1;
    rows_in [tid] = (tid < np) ? pin [k * mcap + p0 + tid] : -1;
  }

  int wave = tid >> 6, lane = tid & 63;
  int wm = (wave & 1) * 32, wn = (wave >> 1) * 64;
  int lm = lane & 15, quad = lane >> 4;
  const short* Wk = Wt + (size_t)k * cout * cin;
  int nT = (cout + 127) >> 7;

  for (int ks = 0; ks < cin_pad; ks += 256) {
    int kslab = min(256, cin_pad - ks);
    __syncthreads();  // protects Alds reuse + rows_* first pass
    int chunks = kslab >> 3;
    for (int u = tid; u < 64 * chunks; u += 256) {
      int r = u / chunks;
      int kc = (u - r * chunks) << 3;
      int gk = ks + kc;
      int irow = rows_in[r];
      short8 v = {0, 0, 0, 0, 0, 0, 0, 0};
      if (irow >= 0 && gk < cin) {
        if (AFP32) {
          const float* s = (const float*)Fv + (size_t)irow * cin + gk;
          #pragma unroll
          for (int j = 0; j < 8; ++j) {
            float y = ab[gk + j] * s[j] + ab[cin + gk + j];
            y = fmaxf(y, 0.01f * y);
            v[j] = f2bf(y);
          }
        } else {
          v = *(const short8*)((const short*)Fv + (size_t)irow * cin + gk);
        }
      }
      *(short8*)(Alds + r * aStride + kc) = v;
    }
    // A-writes ordered before reads by the first k-loop __syncthreads below.
    for (int nt0 = 0; nt0 < nT; ++nt0) {
      int n0 = nt0 << 7;
      f32x4 acc[2][4] = {};
      for (int k0 = 0; k0 < kslab; k0 += 32) {
        __syncthreads();  // protect Blds overwrite (and A-stage ordering)
        for (int u = tid; u < 512; u += 256) {
          int n = u >> 2, kc = (u & 3) << 3;
          int gn = n0 + n, gk = ks + k0 + kc;
          short8 v = {0, 0, 0, 0, 0, 0, 0, 0};
          if (gn < cout && gk < cin)
            v = *(const short8*)(Wk + (size_t)gn * cin + gk);
          *(short8*)(Blds + n * 40 + kc) = v;
        }
        __syncthreads();
        short8 a0 = *(const short8*)(Alds + (wm + lm) * aStride + k0 + quad * 8);
        short8 a1 = *(const short8*)(Alds + (wm + 16 + lm) * aStride + k0 + quad * 8);
        #pragma unroll
        for (int nt = 0; nt < 4; ++nt) {
          short8 b = *(const short8*)(Blds + (wn + nt * 16 + lm) * 40 + quad * 8);
          acc[0][nt] = __builtin_amdgcn_mfma_f32_16x16x32_bf16(a0, b, acc[0][nt], 0, 0, 0);
          acc[1][nt] = __builtin_amdgcn_mfma_f32_16x16x32_bf16(a1, b, acc[1][nt], 0, 0, 0);
        }
      }
      #pragma unroll
      for (int mt = 0; mt < 2; ++mt)
        #pragma unroll
        for (int nt = 0; nt < 4; ++nt)
          #pragma unroll
          for (int r = 0; r < 4; ++r) {
            int row = wm + mt * 16 + quad * 4 + r;
            int col = n0 + wn + nt * 16 + lm;
            if (row < np && col < cout)
              atomicAdd(&out[(size_t)rows_out[row] * cout + col], acc[mt][nt][r]);
          }
    }
  }
}

// ------------------------------------------- weight convert+transpose to bf16
// Wt[k][n][c] = bf16(W[k][c][n]); grid (cout/32, cin/32, 27), block 256 (32x8)
__global__ void k_convert_w(const float* __restrict__ W, short* __restrict__ Wt,
                            int cin, int cout) {
  __shared__ float tile[32][33];
  int k = blockIdx.z;
  int n0 = blockIdx.x * 32, c0 = blockIdx.y * 32;
  int tx = threadIdx.x & 31, ty = threadIdx.x >> 5;
  const float* Wk = W + (size_t)k * cin * cout;
  for (int i = ty; i < 32; i += 8) {
    int c = c0 + i, n = n0 + tx;
    tile[i][tx] = (c < cin && n < cout) ? Wk[(size_t)c * cout + n] : 0.f;
  }
  __syncthreads();
  short* Wtk = Wt + (size_t)k * cout * cin;
  for (int i = ty; i < 32; i += 8) {
    int n = n0 + i, c = c0 + tx;
    if (n < cout && c < cin) Wtk[(size_t)n * cin + c] = f2bf(tile[tx][i]);
  }
}

// ------------------------------------------------------------------ maxpool
__global__ void k_query_idx(const int* __restrict__ oc, int m, int sh, int Gs,
                            const int* __restrict__ keys, const int* __restrict__ vals,
                            unsigned capmask, int* __restrict__ idx) {
  int t = blockIdx.x * blockDim.x + threadIdx.x;
  if (t >= m * 27) return;
  int o = t / 27, k = t - o * 27;
  int stride = 1 << sh;
  int dx = k / 9 - 1, dy = (k / 3) % 3 - 1, dz = k % 3 - 1;
  int b  = oc[4 * o];
  int qx = oc[4 * o + 1] + dx * stride;
  int qy = oc[4 * o + 2] + dy * stride;
  int qz = oc[4 * o + 3] + dz * stride;
  int res = -1;
  if ((unsigned)qx < GDIM && (unsigned)qy < GDIM && (unsigned)qz < GDIM) {
    int key = ((b * Gs + (qx >> sh)) * Gs + (qy >> sh)) * Gs + (qz >> sh);
    res = hash_lookup(key, keys, vals, capmask);
  }
  idx[t] = res;
}

// fused: y = max over hits of lrelu(a*v+b), emitted as bf16
__global__ void k_maxpool_bn(const float* __restrict__ F, unsigned short* __restrict__ out,
                             const int* __restrict__ idx, int m, int C,
                             const float* __restrict__ ab) {
  long long t = (long long)blockIdx.x * blockDim.x + threadIdx.x;
  if (t >= (long long)m * C) return;
  int o = (int)(t / C), c = (int)(t - (long long)o * C);
  float a = ab[c], b = ab[C + c];
  float best = -3e38f;
  #pragma unroll 1
  for (int k = 0; k < 27; ++k) {
    int i = idx[o * 27 + k];
    if (i >= 0) {
      float y = a * F[(size_t)i * C + c] + b;
      y = fmaxf(y, 0.01f * y);
      best = fmaxf(best, y);
    }
  }
  out[t] = (unsigned short)f2bf(best);
}

// -------------------------------------------------------- slice / gather / mlp
__global__ void k_slice_idx(const int* __restrict__ coords, int n, int sh, int Gs,
                            const int* __restrict__ keys, const int* __restrict__ vals,
                            unsigned capmask, int* __restrict__ sidx) {
  int i = blockIdx.x * blockDim.x + threadIdx.x;
  if (i >= n) return;
  int b = coords[4 * i];
  int key = ((b * Gs + (coords[4 * i + 1] >> sh)) * Gs + (coords[4 * i + 2] >> sh)) * Gs +
            (coords[4 * i + 3] >> sh);
  int v = hash_lookup(key, keys, vals, capmask);
  sidx[i] = (v < 0) ? 0 : v;
}

__global__ void k_gather_cols16(const unsigned short* __restrict__ src, int C,
                                const int* __restrict__ sidx,
                                unsigned short* __restrict__ dst, int dstC, int colOff, int n) {
  long long t = (long long)blockIdx.x * blockDim.x + threadIdx.x;
  if (t >= (long long)n * C) return;
  int o = (int)(t / C), c = (int)(t - (long long)o * C);
  dst[(size_t)o * dstC + colOff + c] = src[(size_t)sidx[o] * C + c];
}

__global__ void k_mlp(const float* __restrict__ feats, const float* __restrict__ w,
                      float* __restrict__ x, int n) {
  int t = blockIdx.x * blockDim.x + threadIdx.x;
  if (t >= n * 32) return;
  x[t] = feats[t >> 5] * w[t & 31];
}

// ----------------------------------------------------------------------- BN
__global__ void k_bn_stats(const float* __restrict__ x, int m, int C, float* __restrict__ sums) {
  int r0 = blockIdx.x * 256;
  int rend = min(r0 + 256, m);
  for (int c = threadIdx.x; c < C; c += 256) {
    float s = 0.f, s2 = 0.f;
    for (int r = r0; r < rend; ++r) {
      float v = x[(size_t)r * C + c];
      s += v; s2 += v * v;
    }
    atomicAdd(&sums[c], s);
    atomicAdd(&sums[C + c], s2);
  }
}

__global__ void k_bn_finalize(const float* __restrict__ sums, const float* __restrict__ gamma,
                              const float* __restrict__ beta, int C, float inv_m,
                              float* __restrict__ ab) {
  for (int c = threadIdx.x; c < C; c += 256) {
    float mu  = sums[c] * inv_m;
    float var = sums[C + c] * inv_m - mu * mu;
    float a = rsqrtf(var + 1e-5f) * gamma[c];
    ab[c] = a;
    ab[C + c] = beta[c] - mu * a;
  }
}

__global__ void k_bn_apply(float* __restrict__ x, long long total, int C,
                           const float* __restrict__ ab) {
  long long t = (long long)blockIdx.x * blockDim.x + threadIdx.x;
  if (t >= total) return;
  int c = (int)(t % C);
  float y = ab[c] * x[t] + ab[C + c];
  x[t] = fmaxf(y, 0.01f * y);
}

// ---------------------------------------------------------------------- host
static inline int cdiv(int a, int b) { return (a + b - 1) / b; }

extern "C" void kernel_launch(void* const* d_in, const int* in_sizes, int n_in,
                              void* d_out, int out_size, void* d_ws, size_t ws_size,
                              hipStream_t stream) {
  (void)n_in; (void)out_size; (void)ws_size;
  // setup_inputs() dict order (levels appended LAST):
  const float* feats  = (const float*)d_in[0];
  const int*   coords = (const int*)d_in[1];
  const float* w_mlp = (const float*)d_in[2];
  const float* gm  = (const float*)d_in[3];  const float* bm  = (const float*)d_in[4];
  const float* W1  = (const float*)d_in[5];  const float* g1  = (const float*)d_in[6];  const float* b1  = (const float*)d_in[7];
  const float* W2  = (const float*)d_in[8];  const float* g2  = (const float*)d_in[9];  const float* b2  = (const float*)d_in[10];
  const float* W3  = (const float*)d_in[11]; const float* g3  = (const float*)d_in[12]; const float* b3  = (const float*)d_in[13];
  const float* W4  = (const float*)d_in[14]; const float* g4  = (const float*)d_in[15]; const float* b4  = (const float*)d_in[16];
  const float* W5a = (const float*)d_in[17]; const float* g5a = (const float*)d_in[18]; const float* b5a = (const float*)d_in[19];
  const float* W5b = (const float*)d_in[20]; const float* g5b = (const float*)d_in[21]; const float* b5b = (const float*)d_in[22];
  const float* W5c = (const float*)d_in[23]; const float* g5c = (const float*)d_in[24]; const float* b5c = (const float*)d_in[25];
  const int*   lvl[7];
  for (int i = 0; i < 7; ++i) lvl[i] = (const int*)d_in[26 + i];

  const int N = in_sizes[0];
  int nl[7];
  for (int i = 0; i < 7; ++i) nl[i] = in_sizes[26 + i] / 4;
  const int n2 = nl[0], n4 = nl[1], n8 = nl[2], n16 = nl[3], n32 = nl[4], n64 = nl[5], n128 = nl[6];

  char* ws = (char*)d_ws;
  size_t off = 0;
  auto alloc = [&](size_t bytes) -> char* {
    off = (off + 255) & ~(size_t)255;
    char* p = ws + off;
    off += bytes;
    return p;
  };

  struct Tab { int* keys; int* vals; unsigned mask; int sh; int Gs; int n; const int* src; };
  Tab tab[8];
  const int* tsrc[8] = {coords, lvl[0], lvl[1], lvl[2], lvl[3], lvl[4], lvl[5], lvl[6]};
  int tn[8] = {N, n2, n4, n8, n16, n32, n64, n128};
  for (int i = 0; i < 8; ++i) {
    int cap = 64;
    while (cap < 2 * tn[i]) cap <<= 1;
    tab[i].keys = (int*)alloc((size_t)cap * 4);
    tab[i].vals = (int*)alloc((size_t)cap * 4);
    tab[i].mask = (unsigned)(cap - 1);
    tab[i].sh = i;
    tab[i].Gs = GDIM >> i;
    tab[i].n = tn[i];
    tab[i].src = tsrc[i];
  }

  int* pout   = (int*)alloc((size_t)27 * N * 4);
  int* pin    = (int*)alloc((size_t)27 * N * 4);
  int* counts = (int*)alloc(256);
  int* idxbuf = (int*)alloc((size_t)27 * N * 4);
  int* sidx[4];
  for (int i = 0; i < 4; ++i) sidx[i] = (int*)alloc((size_t)N * 4);
  float* bnsum = (float*)alloc(2 * 1024 * 4);
  float* abuf  = (float*)alloc(2 * 1024 * 4);

  auto mxz = [](size_t a, size_t b) { return a > b ? a : b; };
  size_t szA = mxz(mxz((size_t)N * 32, (size_t)n4 * 64), (size_t)n64 * 128) * 4;  // x / t2 / t4
  size_t szB = mxz(mxz((size_t)N * 48, (size_t)n16 * 96), (size_t)n2 * 256) * 4;  // t1 / t3 / t5a
  float* RA = (float*)alloc(szA);
  float* RB = (float*)alloc(szB);
  float* RG = (float*)alloc((size_t)n4 * 512 * 4);                                 // t5b
  unsigned short* y1b = (unsigned short*)alloc((size_t)n2 * 48 * 2);
  unsigned short* y2b = (unsigned short*)alloc((size_t)n8 * 64 * 2);
  unsigned short* y3b = (unsigned short*)alloc((size_t)n32 * 96 * 2);
  unsigned short* y4b = (unsigned short*)alloc((size_t)n128 * 128 * 2);
  unsigned short* xcb = (unsigned short*)alloc((size_t)N * 336 * 2);
  short* Wt1  = (short*)alloc((size_t)27 * 32 * 48 * 2);
  short* Wt2  = (short*)alloc((size_t)27 * 48 * 64 * 2);
  short* Wt3  = (short*)alloc((size_t)27 * 64 * 96 * 2);
  short* Wt4  = (short*)alloc((size_t)27 * 96 * 128 * 2);
  short* Wt5a = (short*)alloc((size_t)27 * 336 * 256 * 2);
  short* Wt5b = (short*)alloc((size_t)27 * 256 * 512 * 2);
  short* Wt5c = (short*)alloc((size_t)27 * 512 * 1024 * 2);

  // hash tables
  for (int i = 0; i < 8; ++i)
    hipMemsetAsync(tab[i].keys, 0xFF, (size_t)(tab[i].mask + 1) * 4, stream);
  for (int i = 0; i < 8; ++i)
    k_build_table<<<cdiv(tab[i].n, 256), 256, 0, stream>>>(
        tab[i].src, tab[i].n, tab[i].sh, tab[i].Gs, tab[i].keys, tab[i].vals, tab[i].mask);

  // weight conversion (fp32 [27][cin][cout] -> bf16 [27][cout][cin])
  auto convW = [&](const float* W, short* Wt, int cin, int cout) {
    dim3 g(cdiv(cout, 32), cdiv(cin, 32), 27);
    k_convert_w<<<g, 256, 0, stream>>>(W, Wt, cin, cout);
  };
  convW(W1, Wt1, 32, 48);     convW(W2, Wt2, 48, 64);
  convW(W3, Wt3, 64, 96);     convW(W4, Wt4, 96, 128);
  convW(W5a, Wt5a, 336, 256); convW(W5b, Wt5b, 256, 512);
  convW(W5c, Wt5c, 512, 1024);

  auto conv = [&](const void* F, bool afp32, const short* Wt, const int* oc, int m,
                  const Tab& t, int cin, int cout, float* out) {
    hipMemsetAsync(counts, 0, 27 * 4, stream);
    k_query_pairs<<<cdiv(m * 27, 256), 256, 0, stream>>>(
        oc, m, t.sh, t.Gs, t.keys, t.vals, t.mask, pout, pin, counts, N);
    hipMemsetAsync(out, 0, (size_t)m * cout * 4, stream);
    int cin_pad = (cin + 31) & ~31;
    int aStride = (cin_pad < 256 ? cin_pad : 256) + 8;
    size_t shmem = (size_t)64 * aStride * 2 + 128 * 40 * 2 + 2 * 64 * 4;
    dim3 grid(cdiv(m, 64), 1, 27);
    if (afp32)
      k_conv_mfma<true><<<grid, 256, shmem, stream>>>(F, abuf, Wt, out, pout, pin, counts,
                                                      cin, cin_pad, cout, N);
    else
      k_conv_mfma<false><<<grid, 256, shmem, stream>>>(F, abuf, Wt, out, pout, pin, counts,
                                                       cin, cin_pad, cout, N);
  };
  auto stats = [&](const float* x, int m, int C, const float* gamma, const float* beta) {
    hipMemsetAsync(bnsum, 0, (size_t)2 * C * 4, stream);
    k_bn_stats<<<cdiv(m, 256), 256, 0, stream>>>(x, m, C, bnsum);
    k_bn_finalize<<<1, 256, 0, stream>>>(bnsum, gamma, beta, C, 1.0f / (float)m, abuf);
  };
  auto pool = [&](const float* F, const int* oc, int m, const Tab& t, int C,
                  unsigned short* out) {
    k_query_idx<<<cdiv(m * 27, 256), 256, 0, stream>>>(
        oc, m, t.sh, t.Gs, t.keys, t.vals, t.mask, idxbuf);
    long long total = (long long)m * C;
    k_maxpool_bn<<<(int)((total + 255) / 256), 256, 0, stream>>>(F, out, idxbuf, m, C, abuf);
  };

  // ---- network ----
  float* x = RA;
  k_mlp<<<cdiv(N * 32, 256), 256, 0, stream>>>(feats, w_mlp, x, N);
  stats(x, N, 32, gm, bm);                       // abuf = mlp bn

  float* t1 = RB;
  conv(x, true, Wt1, coords, N, tab[0], 32, 48, t1);   // bn fused into A-staging
  stats(t1, N, 48, g1, b1);
  pool(t1, lvl[0], n2, tab[0], 48, y1b);

  float* t2 = RA;
  conv(y1b, false, Wt2, lvl[1], n4, tab[1], 48, 64, t2);
  stats(t2, n4, 64, g2, b2);
  pool(t2, lvl[2], n8, tab[2], 64, y2b);

  float* t3 = RB;
  conv(y2b, false, Wt3, lvl[3], n16, tab[3], 64, 96, t3);
  stats(t3, n16, 96, g3, b3);
  pool(t3, lvl[4], n32, tab[4], 96, y3b);

  float* t4 = RA;
  conv(y3b, false, Wt4, lvl[5], n64, tab[5], 96, 128, t4);
  stats(t4, n64, 128, g4, b4);
  pool(t4, lvl[6], n128, tab[6], 128, y4b);

  // slice_to_field -> xcb (bf16)
  k_slice_idx<<<cdiv(N, 256), 256, 0, stream>>>(coords, N, tab[1].sh, tab[1].Gs,
                                                tab[1].keys, tab[1].vals, tab[1].mask, sidx[0]);
  k_slice_idx<<<cdiv(N, 256), 256, 0, stream>>>(coords, N, tab[3].sh, tab[3].Gs,
                                                tab[3].keys, tab[3].vals, tab[3].mask, sidx[1]);
  k_slice_idx<<<cdiv(N, 256), 256, 0, stream>>>(coords, N, tab[5].sh, tab[5].Gs,
                                                tab[5].keys, tab[5].vals, tab[5].mask, sidx[2]);
  k_slice_idx<<<cdiv(N, 256), 256, 0, stream>>>(coords, N, tab[7].sh, tab[7].Gs,
                                                tab[7].keys, tab[7].vals, tab[7].mask, sidx[3]);
  k_gather_cols16<<<(int)(((long long)N * 48 + 255) / 256), 256, 0, stream>>>(y1b, 48, sidx[0], xcb, 336, 0, N);
  k_gather_cols16<<<(int)(((long long)N * 64 + 255) / 256), 256, 0, stream>>>(y2b, 64, sidx[1], xcb, 336, 48, N);
  k_gather_cols16<<<(int)(((long long)N * 96 + 255) / 256), 256, 0, stream>>>(y3b, 96, sidx[2], xcb, 336, 112, N);
  k_gather_cols16<<<(int)(((long long)N * 128 + 255) / 256), 256, 0, stream>>>(y4b, 128, sidx[3], xcb, 336, 208, N);

  float* t5a = RB;
  conv(xcb, false, Wt5a, lvl[0], n2, tab[0], 336, 256, t5a);
  stats(t5a, n2, 256, g5a, b5a);

  float* t5b = RG;
  conv(t5a, true, Wt5b, lvl[1], n4, tab[1], 256, 512, t5b);   // bn(t5a) fused
  stats(t5b, n4, 512, g5b, b5b);

  float* outp = (float*)d_out;
  conv(t5b, true, Wt5c, lvl[2], n8, tab[2], 512, 1024, outp); // bn(t5b) fused
  stats(outp, n8, 1024, g5c, b5c);
  long long total = (long long)n8 * 1024;
  k_bn_apply<<<(int)((total + 255) / 256), 256, 0, stream>>>(outp, total, 1024, abuf);
}